// Round 2
// baseline (448.877 us; speedup 1.0000x reference)
//
#include <hip/hip_runtime.h>

typedef unsigned short u16;
typedef unsigned int u32;
typedef __attribute__((ext_vector_type(4))) float f32x4;
typedef __attribute__((ext_vector_type(8))) short bf16x8;
typedef __attribute__((ext_vector_type(4))) unsigned short u16x4;
typedef __attribute__((ext_vector_type(8))) unsigned short u16x8;

#define NH 16
#define HD 128
#define BB 32
#define TT 256
#define CDIM 2048

__device__ __forceinline__ u16 f2bf(float f) {
  u32 u = __float_as_uint(f);
  u = (u + 0x7fffu + ((u >> 16) & 1u)) >> 16;
  return (u16)u;
}
__device__ __forceinline__ float bf2f(u16 h) {
  return __uint_as_float(((u32)h) << 16);
}
__device__ __forceinline__ void gload_lds16(const u16* g, u16* l) {
  __builtin_amdgcn_global_load_lds((__attribute__((address_space(1))) void*)g,
                                   (__attribute__((address_space(3))) void*)l, 16, 0, 0);
}

// ---------------- convert f32 -> bf16, 8 elems/thread ----------------
__global__ __launch_bounds__(256) void cvt_bf16_kernel(const float* __restrict__ src,
                                                       u16* __restrict__ dst, int n8) {
  int i = blockIdx.x * 256 + threadIdx.x;
  if (i >= n8) return;
  const float4* s4 = (const float4*)src;
  float4 a = s4[i * 2];
  float4 b = s4[i * 2 + 1];
  u16x8 r;
  r[0] = f2bf(a.x); r[1] = f2bf(a.y); r[2] = f2bf(a.z); r[3] = f2bf(a.w);
  r[4] = f2bf(b.x); r[5] = f2bf(b.y); r[6] = f2bf(b.z); r[7] = f2bf(b.w);
  *(u16x8*)(dst + (long)i * 8) = r;
}

// ---------------- rope tables: [256][64] cos,sin ----------------
__global__ void rope_tables_kernel(float* __restrict__ cosT, float* __restrict__ sinT) {
  int i = blockIdx.x * 256 + threadIdx.x;  // 16384
  int t = i >> 6, d = i & 63;
  // inv_freq = 10000^(-(2d)/128) = exp(-d/64 * ln(10000))
  float inv = __expf(-(float)d * (9.210340371976184f / 64.0f));
  float a = (float)t * inv;
  cosT[i] = cosf(a);
  sinT[i] = sinf(a);
}

// ---------------- rope apply in-place on q (scaled) and k ----------------
__global__ __launch_bounds__(256) void rope_apply_kernel(u16* __restrict__ q, u16* __restrict__ k,
                                                         const float* __restrict__ cosT,
                                                         const float* __restrict__ sinT) {
  int idx = blockIdx.x * 256 + threadIdx.x;  // 2 * 2097152
  u16* base;
  float sc;
  int i;
  if (idx < 2097152) { base = q; sc = 0.08838834764831845f; i = idx; }
  else               { base = k; sc = 1.0f;                 i = idx - 2097152; }
  int row = i >> 4, d0 = (i & 15) * 4;
  int t = row & 255;
  u16* p1 = base + (long)row * HD + d0;
  u16* p2 = p1 + 64;
  u16x4 x1 = *(u16x4*)p1;
  u16x4 x2 = *(u16x4*)p2;
  float4 c4 = *(const float4*)(cosT + t * 64 + d0);
  float4 s4 = *(const float4*)(sinT + t * 64 + d0);
  float a0 = bf2f(x1[0]), a1 = bf2f(x1[1]), a2 = bf2f(x1[2]), a3 = bf2f(x1[3]);
  float b0 = bf2f(x2[0]), b1 = bf2f(x2[1]), b2 = bf2f(x2[2]), b3 = bf2f(x2[3]);
  u16x4 o1, o2;
  o1[0] = f2bf((a0 * c4.x - b0 * s4.x) * sc);
  o1[1] = f2bf((a1 * c4.y - b1 * s4.y) * sc);
  o1[2] = f2bf((a2 * c4.z - b2 * s4.z) * sc);
  o1[3] = f2bf((a3 * c4.w - b3 * s4.w) * sc);
  o2[0] = f2bf((b0 * c4.x + a0 * s4.x) * sc);
  o2[1] = f2bf((b1 * c4.y + a1 * s4.y) * sc);
  o2[2] = f2bf((b2 * c4.z + a2 * s4.z) * sc);
  o2[3] = f2bf((b3 * c4.w + a3 * s4.w) * sc);
  *(u16x4*)p1 = o1;
  *(u16x4*)p2 = o2;
}

// ---------------- GEMM C = A * B^T, bf16 inputs, 128x128 tile, BK=64 ----------------
// MODE 0: write f32 to Cf[M][N]
// MODE 1: qkv epilogue: N-tile == one head; write bf16 to Q/K/V in [b][h][t][d]
template <int MODE>
__global__ __launch_bounds__(256, 2) void gemm_bt(const u16* __restrict__ A,
                                                  const u16* __restrict__ Bt,
                                                  float* __restrict__ Cf, u16* __restrict__ Qo,
                                                  u16* __restrict__ Ko, u16* __restrict__ Vo,
                                                  int M, int N, int K) {
  __shared__ u16 Al[128 * 64];
  __shared__ u16 Bl[128 * 64];
  const int bm = blockIdx.y, bn = blockIdx.x;
  const int tid = threadIdx.x, wid = tid >> 6, lane = tid & 63;
  const int lr = lane & 15, lg = lane >> 4;
  const int wm = (wid >> 1) * 64, wn = (wid & 1) * 64;
  const int rowA = tid >> 3, seg = tid & 7;
  const u16* ga = A + (long)(bm * 128 + rowA) * K + seg * 8;
  const u16* gb = Bt + (long)(bn * 128 + rowA) * K + seg * 8;

  const f32x4 zero = {0.f, 0.f, 0.f, 0.f};
  f32x4 acc[4][4];
#pragma unroll
  for (int a = 0; a < 4; ++a)
#pragma unroll
    for (int b = 0; b < 4; ++b) acc[a][b] = zero;

  for (int k0 = 0; k0 < K; k0 += 64) {
    __syncthreads();
#pragma unroll
    for (int i = 0; i < 4; ++i)
      gload_lds16(ga + (long)i * 32 * K + k0, &Al[(i * 32 + rowA) * 64 + seg * 8]);
#pragma unroll
    for (int i = 0; i < 4; ++i)
      gload_lds16(gb + (long)i * 32 * K + k0, &Bl[(i * 32 + rowA) * 64 + seg * 8]);
    __syncthreads();
#pragma unroll
    for (int ks = 0; ks < 2; ++ks) {
      bf16x8 af[4], bfr[4];
#pragma unroll
      for (int f = 0; f < 4; ++f)
        af[f] = *(const bf16x8*)(&Al[(wm + f * 16 + lr) * 64 + ks * 32 + lg * 8]);
#pragma unroll
      for (int f = 0; f < 4; ++f)
        bfr[f] = *(const bf16x8*)(&Bl[(wn + f * 16 + lr) * 64 + ks * 32 + lg * 8]);
#pragma unroll
      for (int fm = 0; fm < 4; ++fm)
#pragma unroll
        for (int fn = 0; fn < 4; ++fn)
          acc[fm][fn] =
              __builtin_amdgcn_mfma_f32_16x16x32_bf16(af[fm], bfr[fn], acc[fm][fn], 0, 0, 0);
    }
  }

  if (MODE == 0) {
#pragma unroll
    for (int fm = 0; fm < 4; ++fm)
#pragma unroll
      for (int fn = 0; fn < 4; ++fn)
#pragma unroll
        for (int r = 0; r < 4; ++r) {
          int m = bm * 128 + wm + fm * 16 + lg * 4 + r;
          int n = bn * 128 + wn + fn * 16 + lr;
          Cf[(long)m * N + n] = acc[fm][fn][r];
        }
  } else {
    const int mat = bn >> 4, head = bn & 15;
    u16* dst = (mat == 0) ? Qo : ((mat == 1) ? Ko : Vo);
#pragma unroll
    for (int fm = 0; fm < 4; ++fm)
#pragma unroll
      for (int fn = 0; fn < 4; ++fn)
#pragma unroll
        for (int r = 0; r < 4; ++r) {
          int m = bm * 128 + wm + fm * 16 + lg * 4 + r;
          int d = wn + fn * 16 + lr;
          int b = m >> 8, t = m & 255;
          dst[(((long)(b * NH + head)) * TT + t) * HD + d] = f2bf(acc[fm][fn][r]);
        }
  }
}

// ---------------- fused causal attention ----------------
// block = (b, h, q-half of 128 rows); 4 waves x 32 q-rows each
__global__ __launch_bounds__(256, 2) void attn_kernel(const u16* __restrict__ Qb,
                                                      const u16* __restrict__ Kb,
                                                      const u16* __restrict__ Vb,
                                                      u16* __restrict__ Ob) {
  __shared__ u16 Ks[64][136];     // K chunk row-major (+8 pad)
  __shared__ u16 Vt[128][72];     // V chunk transposed [d][k] (+8 pad)
  __shared__ u16 Ps[4][32][72];   // per-wave P scratch (+8 pad)
  const int bid = blockIdx.x;
  const int qb = bid & 1, h = (bid >> 1) & 15, b = bid >> 5;
  const int tid = threadIdx.x, wid = tid >> 6, lane = tid & 63;
  const int lr = lane & 15, lg = lane >> 4;
  const u16* qh = Qb + ((long)(b * NH + h)) * TT * HD;
  const u16* kh = Kb + ((long)(b * NH + h)) * TT * HD;
  const u16* vh = Vb + ((long)(b * NH + h)) * TT * HD;
  const int q0 = qb * 128 + wid * 32;

  // Q fragments in registers (q pre-scaled by 1/sqrt(d) in rope)
  bf16x8 qf[2][4];
#pragma unroll
  for (int fq = 0; fq < 2; ++fq)
#pragma unroll
    for (int ds = 0; ds < 4; ++ds)
      qf[fq][ds] = *(const bf16x8*)(qh + (long)(q0 + fq * 16 + lr) * HD + ds * 32 + lg * 8);

  const f32x4 zero = {0.f, 0.f, 0.f, 0.f};
  f32x4 oacc[2][8];
#pragma unroll
  for (int fq = 0; fq < 2; ++fq)
#pragma unroll
    for (int fd = 0; fd < 8; ++fd) oacc[fq][fd] = zero;
  float mrow[2][4], lrow[2][4];
#pragma unroll
  for (int fq = 0; fq < 2; ++fq)
#pragma unroll
    for (int r = 0; r < 4; ++r) { mrow[fq][r] = -1e30f; lrow[fq][r] = 0.f; }

  const int nch = (qb == 0) ? 2 : 4;
  for (int kc = 0; kc < nch; ++kc) {
    __syncthreads();
    // stage K chunk (64 rows x 128 cols) -- 1024 x u16x8 loads
#pragma unroll
    for (int it = 0; it < 4; ++it) {
      int task = it * 256 + tid;
      int r = task >> 4, sg = task & 15;
      u16x8 v = *(const u16x8*)(kh + (long)(kc * 64 + r) * HD + sg * 8);
      *(u16x8*)(&Ks[r][sg * 8]) = v;
    }
    // stage V chunk transposed
#pragma unroll
    for (int it = 0; it < 4; ++it) {
      int task = it * 256 + tid;
      int r = task >> 4, d0 = (task & 15) * 8;
      u16x8 v = *(const u16x8*)(vh + (long)(kc * 64 + r) * HD + d0);
#pragma unroll
      for (int j = 0; j < 8; ++j) Vt[d0 + j][r] = v[j];
    }
    __syncthreads();

    // S = Q K^T  (32 q-rows x 64 k-cols per wave)
    f32x4 sacc[2][4];
#pragma unroll
    for (int fq = 0; fq < 2; ++fq)
#pragma unroll
      for (int fk = 0; fk < 4; ++fk) sacc[fq][fk] = zero;
#pragma unroll
    for (int ds = 0; ds < 4; ++ds) {
      bf16x8 kf[4];
#pragma unroll
      for (int fk = 0; fk < 4; ++fk)
        kf[fk] = *(const bf16x8*)(&Ks[fk * 16 + lr][ds * 32 + lg * 8]);
#pragma unroll
      for (int fq = 0; fq < 2; ++fq)
#pragma unroll
        for (int fk = 0; fk < 4; ++fk)
          sacc[fq][fk] =
              __builtin_amdgcn_mfma_f32_16x16x32_bf16(qf[fq][ds], kf[fk], sacc[fq][fk], 0, 0, 0);
    }

    // causal mask + online softmax, P -> LDS (bf16)
#pragma unroll
    for (int fq = 0; fq < 2; ++fq) {
      float mnew[4], alpha[4], psum[4];
#pragma unroll
      for (int r = 0; r < 4; ++r) {
        int qrow = q0 + fq * 16 + lg * 4 + r;
        float cmax = -1e30f;
#pragma unroll
        for (int fk = 0; fk < 4; ++fk) {
          int kcol = kc * 64 + fk * 16 + lr;
          float s = sacc[fq][fk][r];
          if (kcol > qrow) s = -1e30f;
          sacc[fq][fk][r] = s;
          cmax = fmaxf(cmax, s);
        }
#pragma unroll
        for (int off = 1; off < 16; off <<= 1) cmax = fmaxf(cmax, __shfl_xor(cmax, off));
        mnew[r] = fmaxf(mrow[fq][r], cmax);
        alpha[r] = __expf(mrow[fq][r] - mnew[r]);
        mrow[fq][r] = mnew[r];
        psum[r] = 0.f;
      }
#pragma unroll
      for (int fk = 0; fk < 4; ++fk)
#pragma unroll
        for (int r = 0; r < 4; ++r) {
          float p = __expf(sacc[fq][fk][r] - mnew[r]);
          psum[r] += p;
          Ps[wid][fq * 16 + lg * 4 + r][fk * 16 + lr] = f2bf(p);
        }
#pragma unroll
      for (int r = 0; r < 4; ++r) {
        float ps = psum[r];
#pragma unroll
        for (int off = 1; off < 16; off <<= 1) ps += __shfl_xor(ps, off);
        lrow[fq][r] = lrow[fq][r] * alpha[r] + ps;
#pragma unroll
        for (int fd = 0; fd < 8; ++fd) oacc[fq][fd][r] *= alpha[r];
      }
    }

    // O += P @ V
#pragma unroll
    for (int ks = 0; ks < 2; ++ks) {
      bf16x8 pf0 = *(const bf16x8*)(&Ps[wid][lr][ks * 32 + lg * 8]);
      bf16x8 pf1 = *(const bf16x8*)(&Ps[wid][16 + lr][ks * 32 + lg * 8]);
#pragma unroll
      for (int fd = 0; fd < 8; ++fd) {
        bf16x8 vf = *(const bf16x8*)(&Vt[fd * 16 + lr][ks * 32 + lg * 8]);
        oacc[0][fd] = __builtin_amdgcn_mfma_f32_16x16x32_bf16(pf0, vf, oacc[0][fd], 0, 0, 0);
        oacc[1][fd] = __builtin_amdgcn_mfma_f32_16x16x32_bf16(pf1, vf, oacc[1][fd], 0, 0, 0);
      }
    }
  }

  // normalize + write [b][t][h*128+d] bf16
#pragma unroll
  for (int fq = 0; fq < 2; ++fq)
#pragma unroll
    for (int r = 0; r < 4; ++r) {
      float inv = 1.0f / lrow[fq][r];
      int t = q0 + fq * 16 + lg * 4 + r;
      u16* od = Ob + ((long)(b * TT + t)) * CDIM + h * HD;
#pragma unroll
      for (int fd = 0; fd < 8; ++fd) od[fd * 16 + lr] = f2bf(oacc[fq][fd][r] * inv);
    }
}

extern "C" void kernel_launch(void* const* d_in, const int* in_sizes, int n_in, void* d_out,
                              int out_size, void* d_ws, size_t ws_size, hipStream_t stream) {
  const float* x = (const float*)d_in[0];
  // d_in[1] = mask (causal; implemented analytically)
  const float* wq = (const float*)d_in[2];
  const float* wk = (const float*)d_in[3];
  const float* wv = (const float*)d_in[4];
  const float* wo = (const float*)d_in[5];

  char* ws = (char*)d_ws;
  u16* xbf = (u16*)(ws);                     // 32 MB; later reused as attn-out [b][t][c]
  u16* wqkv = (u16*)(ws + 33554432);         // 24 MB  [6144][2048]
  u16* wobf = (u16*)(ws + 58720256);         // 8 MB
  u16* qbf = (u16*)(ws + 67108864);          // 32 MB  [b][h][t][d]
  u16* kbf = (u16*)(ws + 100663296);         // 32 MB
  u16* vbf = (u16*)(ws + 134217728);         // 32 MB
  float* cosT = (float*)(ws + 167772160);    // 64 KB
  float* sinT = (float*)(ws + 167837696);    // 64 KB

  cvt_bf16_kernel<<<8192, 256, 0, stream>>>(x, xbf, 2097152);
  cvt_bf16_kernel<<<2048, 256, 0, stream>>>(wq, wqkv, 524288);
  cvt_bf16_kernel<<<2048, 256, 0, stream>>>(wk, wqkv + 2048 * 2048, 524288);
  cvt_bf16_kernel<<<2048, 256, 0, stream>>>(wv, wqkv + 2 * 2048 * 2048, 524288);
  cvt_bf16_kernel<<<2048, 256, 0, stream>>>(wo, wobf, 524288);
  rope_tables_kernel<<<64, 256, 0, stream>>>(cosT, sinT);

  dim3 g1(48, 64);
  gemm_bt<1><<<g1, 256, 0, stream>>>(xbf, wqkv, nullptr, qbf, kbf, vbf, 8192, 6144, 2048);
  rope_apply_kernel<<<16384, 256, 0, stream>>>(qbf, kbf, cosT, sinT);
  attn_kernel<<<1024, 256, 0, stream>>>(qbf, kbf, vbf, xbf);
  dim3 g2(16, 64);
  gemm_bt<0><<<g2, 256, 0, stream>>>(xbf, wobf, (float*)d_out, nullptr, nullptr, nullptr, 8192,
                                     2048, 2048);
}

// Round 3
// 367.086 us; speedup vs baseline: 1.2228x; 1.2228x over previous
//
#include <hip/hip_runtime.h>

typedef unsigned short u16;
typedef unsigned int u32;
typedef __attribute__((ext_vector_type(4))) float f32x4;
typedef __attribute__((ext_vector_type(8))) short bf16x8;
typedef __attribute__((ext_vector_type(4))) unsigned short u16x4;
typedef __attribute__((ext_vector_type(8))) unsigned short u16x8;

#define NH 16
#define HD 128
#define TT 256
#define CDIM 2048

__device__ __forceinline__ u16 f2bf(float f) {
  u32 u = __float_as_uint(f);
  u = (u + 0x7fffu + ((u >> 16) & 1u)) >> 16;
  return (u16)u;
}
__device__ __forceinline__ float bf2f(u16 h) {
  return __uint_as_float(((u32)h) << 16);
}
__device__ __forceinline__ void gload_lds16(const u16* g, u16* l) {
  __builtin_amdgcn_global_load_lds((__attribute__((address_space(1))) void*)g,
                                   (__attribute__((address_space(3))) void*)l, 16, 0, 0);
}

#define BAR() __builtin_amdgcn_s_barrier()
#define SCB() __builtin_amdgcn_sched_barrier(0)
#define WL0()                                          \
  {                                                    \
    asm volatile("s_waitcnt lgkmcnt(0)" ::: "memory"); \
    SCB();                                             \
  }
#define WV4()                                         \
  {                                                   \
    asm volatile("s_waitcnt vmcnt(4)" ::: "memory");  \
    SCB();                                            \
  }

// ---------------- convert f32 -> bf16, 8 elems/thread ----------------
__global__ __launch_bounds__(256) void cvt_bf16_kernel(const float* __restrict__ src,
                                                       u16* __restrict__ dst, int n8) {
  int i = blockIdx.x * 256 + threadIdx.x;
  if (i >= n8) return;
  const float4* s4 = (const float4*)src;
  float4 a = s4[i * 2];
  float4 b = s4[i * 2 + 1];
  u16x8 r;
  r[0] = f2bf(a.x); r[1] = f2bf(a.y); r[2] = f2bf(a.z); r[3] = f2bf(a.w);
  r[4] = f2bf(b.x); r[5] = f2bf(b.y); r[6] = f2bf(b.z); r[7] = f2bf(b.w);
  *(u16x8*)(dst + (long)i * 8) = r;
}

// all four weight matrices in one launch: blocks [0,8192), 2048 per matrix
__global__ __launch_bounds__(256) void cvt_w_kernel(const float* __restrict__ wq,
                                                    const float* __restrict__ wk,
                                                    const float* __restrict__ wv,
                                                    const float* __restrict__ wo,
                                                    u16* __restrict__ wqkv,
                                                    u16* __restrict__ wobf) {
  int i = blockIdx.x * 256 + threadIdx.x;
  int seg = i >> 19;  // 524288 u16x8-tasks per matrix
  int r8 = i & 524287;
  const float* s = (seg == 0) ? wq : (seg == 1) ? wk : (seg == 2) ? wv : wo;
  u16* d = (seg == 3) ? wobf : (wqkv + (long)seg * 4194304);
  const float4* s4 = (const float4*)s;
  float4 a = s4[r8 * 2];
  float4 b = s4[r8 * 2 + 1];
  u16x8 r;
  r[0] = f2bf(a.x); r[1] = f2bf(a.y); r[2] = f2bf(a.z); r[3] = f2bf(a.w);
  r[4] = f2bf(b.x); r[5] = f2bf(b.y); r[6] = f2bf(b.z); r[7] = f2bf(b.w);
  *(u16x8*)(d + (long)r8 * 8) = r;
}

// ---------------- rope tables: [256][64] cos,sin ----------------
__global__ void rope_tables_kernel(float* __restrict__ cosT, float* __restrict__ sinT) {
  int i = blockIdx.x * 256 + threadIdx.x;  // 16384
  int t = i >> 6, d = i & 63;
  float inv = __expf(-(float)d * (9.210340371976184f / 64.0f));
  float a = (float)t * inv;
  cosT[i] = cosf(a);
  sinT[i] = sinf(a);
}

// ---------------- rope apply in-place on q (scaled) and k ----------------
__global__ __launch_bounds__(256) void rope_apply_kernel(u16* __restrict__ q, u16* __restrict__ k,
                                                         const float* __restrict__ cosT,
                                                         const float* __restrict__ sinT) {
  int idx = blockIdx.x * 256 + threadIdx.x;  // 2 * 2097152
  u16* base;
  float sc;
  int i;
  if (idx < 2097152) { base = q; sc = 0.08838834764831845f; i = idx; }
  else               { base = k; sc = 1.0f;                 i = idx - 2097152; }
  int row = i >> 4, d0 = (i & 15) * 4;
  int t = row & 255;
  u16* p1 = base + (long)row * HD + d0;
  u16* p2 = p1 + 64;
  u16x4 x1 = *(u16x4*)p1;
  u16x4 x2 = *(u16x4*)p2;
  float4 c4 = *(const float4*)(cosT + t * 64 + d0);
  float4 s4 = *(const float4*)(sinT + t * 64 + d0);
  float a0 = bf2f(x1[0]), a1 = bf2f(x1[1]), a2 = bf2f(x1[2]), a3 = bf2f(x1[3]);
  float b0 = bf2f(x2[0]), b1 = bf2f(x2[1]), b2 = bf2f(x2[2]), b3 = bf2f(x2[3]);
  u16x4 o1, o2;
  o1[0] = f2bf((a0 * c4.x - b0 * s4.x) * sc);
  o1[1] = f2bf((a1 * c4.y - b1 * s4.y) * sc);
  o1[2] = f2bf((a2 * c4.z - b2 * s4.z) * sc);
  o1[3] = f2bf((a3 * c4.w - b3 * s4.w) * sc);
  o2[0] = f2bf((b0 * c4.x + a0 * s4.x) * sc);
  o2[1] = f2bf((b1 * c4.y + a1 * s4.y) * sc);
  o2[2] = f2bf((b2 * c4.z + a2 * s4.z) * sc);
  o2[3] = f2bf((b3 * c4.w + a3 * s4.w) * sc);
  *(u16x4*)p1 = o1;
  *(u16x4*)p2 = o2;
}

// ---------------- 256x256 8-phase GEMM  C = A * B^T ----------------
// 512 threads = 8 waves (2 M x 4 N), BK=64, 2 K-tiles per iteration,
// LDS 128 KiB double-buffered, T2 slot-swizzle, counted vmcnt (T4), setprio (T5).
// MODE 0: f32 C[M][N].  MODE 1: qkv epilogue -> bf16 [b][h][t][d] per head.
#define MM(MH, NH)                                                              \
  _Pragma("unroll") for (int ks = 0; ks < 2; ++ks)                              \
  _Pragma("unroll") for (int f = 0; f < 4; ++f)                                 \
  _Pragma("unroll") for (int fn = 0; fn < 2; ++fn)                              \
      acc[(MH)*4 + f][(NH)*2 + fn] = __builtin_amdgcn_mfma_f32_16x16x32_bf16(   \
          fa[f][ks], fb[fn][ks], acc[(MH)*4 + f][(NH)*2 + fn], 0, 0, 0);

template <int MODE>
__global__ __launch_bounds__(512, 2) void gemm256(const u16* __restrict__ A,
                                                  const u16* __restrict__ Bt,
                                                  float* __restrict__ Cf, u16* __restrict__ Qo,
                                                  u16* __restrict__ Ko, u16* __restrict__ Vo,
                                                  int M, int N, int K) {
  __shared__ u16 lds[65536];  // [buf0.A 16384][buf0.B][buf1.A][buf1.B] u16
  const int bn = blockIdx.x, bm = blockIdx.y;
  const int tid = threadIdx.x, wid = tid >> 6, lane = tid & 63;
  const int lr = lane & 15, lg = lane >> 4;
  const int wm = (wid >> 2) * 128, wn = (wid & 3) * 64;
  const int NT = K >> 6;
  const u16* Ag = A + (long)(bm * 256) * K;
  const u16* Bg = Bt + (long)(bn * 256) * K;

  // stage one half-tile (128 rows x 64 cols): 2 x global_load_lds(16B) per thread.
  // LDS dest is linear (slot s), global source column is swizzle^-1 (involution).
  auto STG = [&](int matbase, int h, const u16* Gp, int kt) {
    if (kt > NT - 1) kt = NT - 1;
#pragma unroll
    for (int i_ = 0; i_ < 2; ++i_) {
      int s = i_ * 512 + tid;
      int r = h * 128 + (s >> 3);
      int cs = (s & 7) ^ (r & 7);
      gload_lds16(Gp + (long)r * K + kt * 64 + cs * 8, &lds[matbase + h * 8192 + s * 8]);
    }
  };

  bf16x8 fa[4][2], fb[2][2];
  auto LDA_ = [&](int base, int mh) {
#pragma unroll
    for (int f = 0; f < 4; ++f)
#pragma unroll
      for (int ks = 0; ks < 2; ++ks) {
        int r = wm + mh * 64 + f * 16 + lr;
        fa[f][ks] = *(const bf16x8*)&lds[base + r * 64 + ((ks * 4 + lg) ^ (r & 7)) * 8];
      }
  };
  auto LDB_ = [&](int base, int nh) {
#pragma unroll
    for (int fn = 0; fn < 2; ++fn)
#pragma unroll
      for (int ks = 0; ks < 2; ++ks) {
        int r = wn + nh * 32 + fn * 16 + lr;
        fb[fn][ks] = *(const bf16x8*)&lds[base + r * 64 + ((ks * 4 + lg) ^ (r & 7)) * 8];
      }
  };

  const f32x4 zero = {0.f, 0.f, 0.f, 0.f};
  f32x4 acc[8][4];
#pragma unroll
  for (int a = 0; a < 8; ++a)
#pragma unroll
    for (int b = 0; b < 4; ++b) acc[a][b] = zero;

  // prologue: buf0 fully (tile 0), buf1.A0 + buf1.B1 (tile 1)
  STG(0, 0, Ag, 0);
  STG(0, 1, Ag, 0);
  STG(16384, 0, Bg, 0);
  STG(16384, 1, Bg, 0);
  STG(32768, 0, Ag, 1);
  STG(49152, 1, Bg, 1);
  WV4();
  BAR();

  const int J = NT >> 1;
  for (int j = 0; j < J; ++j) {
    const int t1 = 2 * j + 1, tn0 = 2 * j + 2, tn1 = 2 * j + 3;
    // p1: Q(0,0) of t0 from buf0; stage buf1.A1 <- t1
    LDA_(0, 0); LDB_(16384, 0);
    STG(32768, 1, Ag, t1);
    BAR(); WL0();
    __builtin_amdgcn_s_setprio(1); MM(0, 0) __builtin_amdgcn_s_setprio(0);
    BAR();
    // p2: Q(0,1); stage buf1.B0 <- t1
    LDB_(16384, 1);
    STG(49152, 0, Bg, t1);
    BAR(); WL0();
    __builtin_amdgcn_s_setprio(1); MM(0, 1) __builtin_amdgcn_s_setprio(0);
    BAR();
    // p3: Q(1,1); stage buf0.A0 <- t0+2
    LDA_(0, 1);
    STG(0, 0, Ag, tn0);
    BAR(); WL0();
    __builtin_amdgcn_s_setprio(1); MM(1, 1) __builtin_amdgcn_s_setprio(0);
    BAR();
    // p4: Q(1,0); stage buf0.B1 <- t0+2; counted wait -> buf1 ready
    LDB_(16384, 0);
    STG(16384, 1, Bg, tn0);
    BAR(); WL0();
    __builtin_amdgcn_s_setprio(1); MM(1, 0) __builtin_amdgcn_s_setprio(0);
    WV4();
    BAR();
    // p5: Q(0,0) of t1 from buf1; stage buf0.B0 <- t0+2
    LDA_(32768, 0); LDB_(49152, 0);
    STG(16384, 0, Bg, tn0);
    BAR(); WL0();
    __builtin_amdgcn_s_setprio(1); MM(0, 0) __builtin_amdgcn_s_setprio(0);
    BAR();
    // p6: Q(0,1); stage buf0.A1 <- t0+2
    LDB_(49152, 1);
    STG(0, 1, Ag, tn0);
    BAR(); WL0();
    __builtin_amdgcn_s_setprio(1); MM(0, 1) __builtin_amdgcn_s_setprio(0);
    BAR();
    // p7: Q(1,1); stage buf1.A0 <- t1+2
    LDA_(32768, 1);
    STG(32768, 0, Ag, tn1);
    BAR(); WL0();
    __builtin_amdgcn_s_setprio(1); MM(1, 1) __builtin_amdgcn_s_setprio(0);
    BAR();
    // p8: Q(1,0); stage buf1.B1 <- t1+2; counted wait -> buf0 ready
    LDB_(49152, 0);
    STG(49152, 1, Bg, tn1);
    BAR(); WL0();
    __builtin_amdgcn_s_setprio(1); MM(1, 0) __builtin_amdgcn_s_setprio(0);
    WV4();
    BAR();
  }

  // epilogue
  if (MODE == 0) {
#pragma unroll
    for (int am = 0; am < 8; ++am)
#pragma unroll
      for (int an = 0; an < 4; ++an)
#pragma unroll
        for (int r = 0; r < 4; ++r) {
          int m = bm * 256 + wm + am * 16 + lg * 4 + r;
          int n = bn * 256 + wn + an * 16 + lr;
          Cf[(long)m * N + n] = acc[am][an][r];
        }
  } else {
#pragma unroll
    for (int am = 0; am < 8; ++am)
#pragma unroll
      for (int an = 0; an < 4; ++an)
#pragma unroll
        for (int r = 0; r < 4; ++r) {
          int m = bm * 256 + wm + am * 16 + lg * 4 + r;
          int n = bn * 256 + wn + an * 16 + lr;
          int mat = n >> 11, head = (n >> 7) & 15, d = n & 127;
          u16* dst = (mat == 0) ? Qo : ((mat == 1) ? Ko : Vo);
          int b = m >> 8, t = m & 255;
          dst[(((long)(b * NH + head)) * TT + t) * HD + d] = f2bf(acc[am][an][r]);
        }
  }
}

// ---------------- fused causal attention ----------------
__global__ __launch_bounds__(256, 2) void attn_kernel(const u16* __restrict__ Qb,
                                                      const u16* __restrict__ Kb,
                                                      const u16* __restrict__ Vb,
                                                      u16* __restrict__ Ob) {
  __shared__ u16 Ks[64][136];
  __shared__ u16 Vt[128][72];
  __shared__ u16 Ps[4][32][72];
  const int bid = blockIdx.x;
  const int qb = bid & 1, h = (bid >> 1) & 15, b = bid >> 5;
  const int tid = threadIdx.x, wid = tid >> 6, lane = tid & 63;
  const int lr = lane & 15, lg = lane >> 4;
  const u16* qh = Qb + ((long)(b * NH + h)) * TT * HD;
  const u16* kh = Kb + ((long)(b * NH + h)) * TT * HD;
  const u16* vh = Vb + ((long)(b * NH + h)) * TT * HD;
  const int q0 = qb * 128 + wid * 32;

  bf16x8 qf[2][4];
#pragma unroll
  for (int fq = 0; fq < 2; ++fq)
#pragma unroll
    for (int ds = 0; ds < 4; ++ds)
      qf[fq][ds] = *(const bf16x8*)(qh + (long)(q0 + fq * 16 + lr) * HD + ds * 32 + lg * 8);

  const f32x4 zero = {0.f, 0.f, 0.f, 0.f};
  f32x4 oacc[2][8];
#pragma unroll
  for (int fq = 0; fq < 2; ++fq)
#pragma unroll
    for (int fd = 0; fd < 8; ++fd) oacc[fq][fd] = zero;
  float mrow[2][4], lrow[2][4];
#pragma unroll
  for (int fq = 0; fq < 2; ++fq)
#pragma unroll
    for (int r = 0; r < 4; ++r) { mrow[fq][r] = -1e30f; lrow[fq][r] = 0.f; }

  const int nch = (qb == 0) ? 2 : 4;
  for (int kc = 0; kc < nch; ++kc) {
    __syncthreads();
#pragma unroll
    for (int it = 0; it < 4; ++it) {
      int task = it * 256 + tid;
      int r = task >> 4, sg = task & 15;
      u16x8 v = *(const u16x8*)(kh + (long)(kc * 64 + r) * HD + sg * 8);
      *(u16x8*)(&Ks[r][sg * 8]) = v;
    }
#pragma unroll
    for (int it = 0; it < 4; ++it) {
      int task = it * 256 + tid;
      int r = task >> 4, d0 = (task & 15) * 8;
      u16x8 v = *(const u16x8*)(vh + (long)(kc * 64 + r) * HD + d0);
#pragma unroll
      for (int j = 0; j < 8; ++j) Vt[d0 + j][r] = v[j];
    }
    __syncthreads();

    f32x4 sacc[2][4];
#pragma unroll
    for (int fq = 0; fq < 2; ++fq)
#pragma unroll
      for (int fk = 0; fk < 4; ++fk) sacc[fq][fk] = zero;
#pragma unroll
    for (int ds = 0; ds < 4; ++ds) {
      bf16x8 kf[4];
#pragma unroll
      for (int fk = 0; fk < 4; ++fk)
        kf[fk] = *(const bf16x8*)(&Ks[fk * 16 + lr][ds * 32 + lg * 8]);
#pragma unroll
      for (int fq = 0; fq < 2; ++fq)
#pragma unroll
        for (int fk = 0; fk < 4; ++fk)
          sacc[fq][fk] =
              __builtin_amdgcn_mfma_f32_16x16x32_bf16(qf[fq][ds], kf[fk], sacc[fq][fk], 0, 0, 0);
    }

#pragma unroll
    for (int fq = 0; fq < 2; ++fq) {
      float mnew[4], alpha[4], psum[4];
#pragma unroll
      for (int r = 0; r < 4; ++r) {
        int qrow = q0 + fq * 16 + lg * 4 + r;
        float cmax = -1e30f;
#pragma unroll
        for (int fk = 0; fk < 4; ++fk) {
          int kcol = kc * 64 + fk * 16 + lr;
          float s = sacc[fq][fk][r];
          if (kcol > qrow) s = -1e30f;
          sacc[fq][fk][r] = s;
          cmax = fmaxf(cmax, s);
        }
#pragma unroll
        for (int off = 1; off < 16; off <<= 1) cmax = fmaxf(cmax, __shfl_xor(cmax, off));
        mnew[r] = fmaxf(mrow[fq][r], cmax);
        alpha[r] = __expf(mrow[fq][r] - mnew[r]);
        mrow[fq][r] = mnew[r];
        psum[r] = 0.f;
      }
#pragma unroll
      for (int fk = 0; fk < 4; ++fk)
#pragma unroll
        for (int r = 0; r < 4; ++r) {
          float p = __expf(sacc[fq][fk][r] - mnew[r]);
          psum[r] += p;
          Ps[wid][fq * 16 + lg * 4 + r][fk * 16 + lr] = f2bf(p);
        }
#pragma unroll
      for (int r = 0; r < 4; ++r) {
        float ps = psum[r];
#pragma unroll
        for (int off = 1; off < 16; off <<= 1) ps += __shfl_xor(ps, off);
        lrow[fq][r] = lrow[fq][r] * alpha[r] + ps;
#pragma unroll
        for (int fd = 0; fd < 8; ++fd) oacc[fq][fd][r] *= alpha[r];
      }
    }

#pragma unroll
    for (int ks = 0; ks < 2; ++ks) {
      bf16x8 pf0 = *(const bf16x8*)(&Ps[wid][lr][ks * 32 + lg * 8]);
      bf16x8 pf1 = *(const bf16x8*)(&Ps[wid][16 + lr][ks * 32 + lg * 8]);
#pragma unroll
      for (int fd = 0; fd < 8; ++fd) {
        bf16x8 vf = *(const bf16x8*)(&Vt[fd * 16 + lr][ks * 32 + lg * 8]);
        oacc[0][fd] = __builtin_amdgcn_mfma_f32_16x16x32_bf16(pf0, vf, oacc[0][fd], 0, 0, 0);
        oacc[1][fd] = __builtin_amdgcn_mfma_f32_16x16x32_bf16(pf1, vf, oacc[1][fd], 0, 0, 0);
      }
    }
  }

#pragma unroll
  for (int fq = 0; fq < 2; ++fq)
#pragma unroll
    for (int r = 0; r < 4; ++r) {
      float inv = 1.0f / lrow[fq][r];
      int t = q0 + fq * 16 + lg * 4 + r;
      u16* od = Ob + ((long)(b * TT + t)) * CDIM + h * HD;
#pragma unroll
      for (int fd = 0; fd < 8; ++fd) od[fd * 16 + lr] = f2bf(oacc[fq][fd][r] * inv);
    }
}

extern "C" void kernel_launch(void* const* d_in, const int* in_sizes, int n_in, void* d_out,
                              int out_size, void* d_ws, size_t ws_size, hipStream_t stream) {
  const float* x = (const float*)d_in[0];
  const float* wq = (const float*)d_in[2];
  const float* wk = (const float*)d_in[3];
  const float* wv = (const float*)d_in[4];
  const float* wo = (const float*)d_in[5];

  char* ws = (char*)d_ws;
  u16* xbf = (u16*)(ws);                   // 32 MB; later reused as attn-out [b][t][c]
  u16* wqkv = (u16*)(ws + 33554432);       // 24 MB  [6144][2048]
  u16* wobf = (u16*)(ws + 58720256);       // 8 MB
  u16* qbf = (u16*)(ws + 67108864);        // 32 MB  [b][h][t][d]
  u16* kbf = (u16*)(ws + 100663296);       // 32 MB
  u16* vbf = (u16*)(ws + 134217728);       // 32 MB
  float* cosT = (float*)(ws + 167772160);  // 64 KB
  float* sinT = (float*)(ws + 167837696);  // 64 KB

  cvt_bf16_kernel<<<8192, 256, 0, stream>>>(x, xbf, 2097152);
  cvt_w_kernel<<<8192, 256, 0, stream>>>(wq, wk, wv, wo, wqkv, wobf);
  rope_tables_kernel<<<64, 256, 0, stream>>>(cosT, sinT);

  dim3 g1(24, 32);
  gemm256<1><<<g1, 512, 0, stream>>>(xbf, wqkv, nullptr, qbf, kbf, vbf, 8192, 6144, 2048);
  rope_apply_kernel<<<16384, 256, 0, stream>>>(qbf, kbf, cosT, sinT);
  attn_kernel<<<1024, 256, 0, stream>>>(qbf, kbf, vbf, xbf);
  dim3 g2(8, 32);
  gemm256<0><<<g2, 512, 0, stream>>>(xbf, wobf, (float*)d_out, nullptr, nullptr, nullptr, 8192,
                                     2048, 2048);
}